// Round 1
// baseline (944.218 us; speedup 1.0000x reference)
//
#include <hip/hip_runtime.h>
#include <hip/hip_bf16.h>
#include <math.h>

// ---------------- graph build ----------------

__global__ __launch_bounds__(256) void count_kernel(const int* __restrict__ dst,
                                                    int* __restrict__ cnt, int e) {
  int i = blockIdx.x * 256 + threadIdx.x;
  if (i < e) atomicAdd(&cnt[dst[i]], 1);
}

__global__ __launch_bounds__(1024) void scan_kernel(const int* __restrict__ cnt,
                                                    int* __restrict__ row_start, int n) {
  __shared__ int sdata[1024];
  int carry = 0;
  for (int base = 0; base < n; base += 1024) {
    int i = base + (int)threadIdx.x;
    int v = (i < n) ? cnt[i] : 0;
    sdata[threadIdx.x] = v;
    __syncthreads();
    for (int off = 1; off < 1024; off <<= 1) {
      int t = (threadIdx.x >= (unsigned)off) ? sdata[threadIdx.x - off] : 0;
      __syncthreads();
      sdata[threadIdx.x] += t;
      __syncthreads();
    }
    if (i < n) row_start[i] = carry + sdata[threadIdx.x] - v;  // exclusive
    carry += sdata[1023];
    __syncthreads();
  }
  if (threadIdx.x == 0) row_start[n] = carry;
}

__global__ __launch_bounds__(256) void dinv_kernel(const int* __restrict__ cnt,
                                                   float* __restrict__ dinv, int n) {
  int i = blockIdx.x * 256 + threadIdx.x;
  if (i < n) dinv[i] = (float)(1.0 / sqrt((double)(cnt[i] + 1)));  // +1 self-loop
}

__global__ __launch_bounds__(256) void fill_kernel(const int* __restrict__ src,
                                                   const int* __restrict__ dst,
                                                   const int* __restrict__ row_start,
                                                   int* __restrict__ cursor,
                                                   int* __restrict__ csr_src, int e) {
  int i = blockIdx.x * 256 + threadIdx.x;
  if (i < e) {
    int d = dst[i];
    int pos = row_start[d] + atomicAdd(&cursor[d], 1);
    csr_src[pos] = src[i];
  }
}

// ---------------- dense GEMM: T = H @ W  (W staged in LDS) ----------------

template <int IN, int OUT>
__global__ __launch_bounds__(256) void gemm_kernel(const float* __restrict__ H,
                                                   const float* __restrict__ W,
                                                   float* __restrict__ T, int n) {
  __shared__ float Ws[IN * OUT];
  for (int i = threadIdx.x; i < IN * OUT; i += 256) Ws[i] = W[i];
  __syncthreads();
  int node = blockIdx.x * 256 + threadIdx.x;
  if (node >= n) return;
  float h[IN];
  const float4* hrow = reinterpret_cast<const float4*>(H + (size_t)node * IN);
#pragma unroll
  for (int k4 = 0; k4 < IN / 4; ++k4) {
    float4 v = hrow[k4];
    h[k4 * 4 + 0] = v.x; h[k4 * 4 + 1] = v.y;
    h[k4 * 4 + 2] = v.z; h[k4 * 4 + 3] = v.w;
  }
  float* out = T + (size_t)node * OUT;
#pragma unroll 1
  for (int j = 0; j < OUT; j += 4) {
    float ax = 0.f, ay = 0.f, az = 0.f, aw = 0.f;
#pragma unroll
    for (int k = 0; k < IN; ++k) {
      float4 w = *reinterpret_cast<const float4*>(&Ws[k * OUT + j]);
      ax = fmaf(h[k], w.x, ax); ay = fmaf(h[k], w.y, ay);
      az = fmaf(h[k], w.z, az); aw = fmaf(h[k], w.w, aw);
    }
    float4 r = {ax, ay, az, aw};
    *reinterpret_cast<float4*>(out + j) = r;
  }
}

// ---------------- GCN aggregate: out = relu(sum_in + b), wave per node ----------------

template <int C>  // 64 or 32
__global__ __launch_bounds__(256) void gcn_agg(const float* __restrict__ T,
                                               const int* __restrict__ row_start,
                                               const int* __restrict__ csr_src,
                                               const float* __restrict__ dinv,
                                               const float* __restrict__ b,
                                               float* __restrict__ out, int n) {
  constexpr int SUB = 64 / C;  // 1 (C=64) or 2 (C=32)
  int wid = threadIdx.x >> 6;
  int lane = threadIdx.x & 63;
  int node = blockIdx.x * 4 + wid;
  if (node >= n) return;
  int c = lane % C;
  int k = lane / C;
  int rs = row_start[node], re = row_start[node + 1];
  float dn = dinv[node];
  float acc = 0.f;
  if (k == 0) acc = T[(size_t)node * C + c] * dn * dn;  // self-loop
  for (int i = rs + k; i < re; i += SUB) {
    int s = csr_src[i];  // wave-uniform for SUB==1? no: uniform across lanes (same i)
    float w = dinv[s] * dn;
    acc = fmaf(T[(size_t)s * C + c], w, acc);
  }
  if (SUB == 2) acc += __shfl_down(acc, 32);
  if (lane < C) out[(size_t)node * C + c] = fmaxf(acc + b[c], 0.f);
}

// ---------------- GAT ----------------

__device__ __forceinline__ float lrelu(float v) { return v > 0.f ? v : 0.2f * v; }

__global__ __launch_bounds__(256) void gat_prep(const float* __restrict__ g,
                                                const float* __restrict__ att_src,
                                                const float* __restrict__ att_dst,
                                                float* __restrict__ a_s,
                                                float* __restrict__ a_d, int n) {
  int wid = threadIdx.x >> 6;
  int lane = threadIdx.x & 63;
  int node = blockIdx.x * 4 + wid;
  if (node >= n) return;
  int h = lane >> 4, cc = lane & 15;
  float gv = g[(size_t)node * 64 + lane];
  float ps = gv * att_src[lane];  // att_src is [4,16] flat == lane
  float pd = gv * att_dst[lane];
#pragma unroll
  for (int off = 8; off >= 1; off >>= 1) {
    ps += __shfl_xor(ps, off);
    pd += __shfl_xor(pd, off);
  }
  if (cc == 0) {
    a_s[(size_t)node * 4 + h] = ps;
    a_d[(size_t)node * 4 + h] = pd;
  }
}

__global__ __launch_bounds__(256) void gat_agg(const float* __restrict__ g,
                                               const float* __restrict__ a_s,
                                               const float* __restrict__ a_d,
                                               const int* __restrict__ row_start,
                                               const int* __restrict__ csr_src,
                                               const float* __restrict__ bg,
                                               float* __restrict__ out, int n) {
  int wid = threadIdx.x >> 6;
  int lane = threadIdx.x & 63;
  int node = blockIdx.x * 4 + wid;
  if (node >= n) return;
  int h = lane >> 4;
  int rs = row_start[node], re = row_start[node + 1];
  float4 ad4 = *reinterpret_cast<const float4*>(a_d + (size_t)node * 4);
  float4 asn4 = *reinterpret_cast<const float4*>(a_s + (size_t)node * 4);
  // pass A: per-head max over {self, in-edges}
  float4 m4;
  m4.x = lrelu(asn4.x + ad4.x); m4.y = lrelu(asn4.y + ad4.y);
  m4.z = lrelu(asn4.z + ad4.z); m4.w = lrelu(asn4.w + ad4.w);
  for (int i = rs + lane; i < re; i += 64) {
    int s = csr_src[i];
    float4 as4 = *reinterpret_cast<const float4*>(a_s + (size_t)s * 4);
    m4.x = fmaxf(m4.x, lrelu(as4.x + ad4.x));
    m4.y = fmaxf(m4.y, lrelu(as4.y + ad4.y));
    m4.z = fmaxf(m4.z, lrelu(as4.z + ad4.z));
    m4.w = fmaxf(m4.w, lrelu(as4.w + ad4.w));
  }
#pragma unroll
  for (int off = 32; off >= 1; off >>= 1) {
    m4.x = fmaxf(m4.x, __shfl_xor(m4.x, off));
    m4.y = fmaxf(m4.y, __shfl_xor(m4.y, off));
    m4.z = fmaxf(m4.z, __shfl_xor(m4.z, off));
    m4.w = fmaxf(m4.w, __shfl_xor(m4.w, off));
  }
  float m_h  = (h == 0) ? m4.x  : (h == 1) ? m4.y  : (h == 2) ? m4.z  : m4.w;
  float ad_h = (h == 0) ? ad4.x : (h == 1) ? ad4.y : (h == 2) ? ad4.z : ad4.w;
  float as_n = (h == 0) ? asn4.x : (h == 1) ? asn4.y : (h == 2) ? asn4.z : asn4.w;
  // pass B: whole wave per edge; accumulate exp-weights and weighted g rows
  float wself = __expf(lrelu(as_n + ad_h) - m_h);
  float den = wself;
  float acc = wself * g[(size_t)node * 64 + lane];
  for (int i = rs; i < re; ++i) {
    int s = csr_src[i];  // uniform across wave -> broadcast
    float as_h = a_s[(size_t)s * 4 + h];
    float w = __expf(lrelu(as_h + ad_h) - m_h);
    den += w;
    acc = fmaf(w, g[(size_t)s * 64 + lane], acc);
  }
  float o = acc / den + bg[lane];
  out[(size_t)node * 64 + lane] = fmaxf(o, 0.f);
}

// ---------------- pooling + classifier ----------------

__global__ __launch_bounds__(256) void pool_partial(const float* __restrict__ O,
                                                    double* __restrict__ partial, int n) {
  int lane_c = threadIdx.x & 63;
  int sub = threadIdx.x >> 6;  // 0..3
  int chunk = (n + gridDim.x - 1) / gridDim.x;
  int r0 = blockIdx.x * chunk;
  int r1 = min(n, r0 + chunk);
  double acc = 0.0;
  for (int r = r0 + sub; r < r1; r += 4)
    acc += (double)O[(size_t)r * 64 + lane_c];
  __shared__ double red[256];
  red[threadIdx.x] = acc;
  __syncthreads();
  if (sub == 0) {
    acc = red[lane_c] + red[64 + lane_c] + red[128 + lane_c] + red[192 + lane_c];
    partial[(size_t)blockIdx.x * 64 + lane_c] = acc;
  }
}

__global__ __launch_bounds__(64) void final_kernel(const double* __restrict__ partial, int nblocks,
                                                   const float* __restrict__ Wc1,
                                                   const float* __restrict__ bc1,
                                                   const float* __restrict__ Wc2,
                                                   const float* __restrict__ bc2,
                                                   float* __restrict__ out, int n) {
  __shared__ float pooled[64];
  __shared__ float z[32];
  int t = threadIdx.x;
  double s = 0.0;
  for (int b = 0; b < nblocks; ++b) s += partial[(size_t)b * 64 + t];
  pooled[t] = (float)(s / (double)n);
  __syncthreads();
  if (t < 32) {
    double a = 0.0;
    for (int k = 0; k < 64; ++k) a += (double)pooled[k] * (double)Wc1[k * 32 + t];
    z[t] = fmaxf((float)a + bc1[t], 0.f);
  }
  __syncthreads();
  if (t < 2) {
    double a = 0.0;
    for (int j = 0; j < 32; ++j) a += (double)z[j] * (double)Wc2[j * 2 + t];
    out[t] = (float)a + bc2[t];
  }
}

// ---------------- launch ----------------

extern "C" void kernel_launch(void* const* d_in, const int* in_sizes, int n_in,
                              void* d_out, int out_size, void* d_ws, size_t ws_size,
                              hipStream_t stream) {
  const float* x   = (const float*)d_in[0];
  const int* eidx  = (const int*)d_in[1];
  const float* W1  = (const float*)d_in[2];
  const float* b1  = (const float*)d_in[3];
  const float* W2  = (const float*)d_in[4];
  const float* b2  = (const float*)d_in[5];
  const float* W3  = (const float*)d_in[6];
  const float* b3  = (const float*)d_in[7];
  const float* Wg  = (const float*)d_in[8];
  const float* att_src = (const float*)d_in[9];
  const float* att_dst = (const float*)d_in[10];
  const float* bg  = (const float*)d_in[11];
  const float* Wc1 = (const float*)d_in[12];
  const float* bc1 = (const float*)d_in[13];
  const float* Wc2 = (const float*)d_in[14];
  const float* bc2 = (const float*)d_in[15];

  const int n = in_sizes[0] / 64;   // 100000
  const int e = in_sizes[1] / 2;    // 1200000
  const int* src = eidx;
  const int* dst = eidx + e;

  char* ws = (char*)d_ws;
  size_t off = 0;
  auto alloc = [&](size_t bytes) {
    void* p = ws + off;
    off += (bytes + 255) & ~(size_t)255;
    return p;
  };
  int*    cnt       = (int*)alloc((size_t)n * 4);
  int*    row_start = (int*)alloc(((size_t)n + 1) * 4);
  int*    cursor    = (int*)alloc((size_t)n * 4);
  int*    csr_src   = (int*)alloc((size_t)e * 4);
  float*  dinv      = (float*)alloc((size_t)n * 4);
  float*  bufA      = (float*)alloc((size_t)n * 64 * 4);
  float*  bufB      = (float*)alloc((size_t)n * 64 * 4);
  float*  a_s       = (float*)alloc((size_t)n * 4 * 4);
  float*  a_d       = (float*)alloc((size_t)n * 4 * 4);
  const int PBLK = 128;
  double* partial   = (double*)alloc((size_t)PBLK * 64 * 8);

  hipMemsetAsync(cnt, 0, (size_t)n * 4, stream);
  hipMemsetAsync(cursor, 0, (size_t)n * 4, stream);

  int eblk = (e + 255) / 256;
  int nblk256 = (n + 255) / 256;
  int nblk4 = (n + 3) / 4;

  count_kernel<<<eblk, 256, 0, stream>>>(dst, cnt, e);
  scan_kernel<<<1, 1024, 0, stream>>>(cnt, row_start, n);
  dinv_kernel<<<nblk256, 256, 0, stream>>>(cnt, dinv, n);
  fill_kernel<<<eblk, 256, 0, stream>>>(src, dst, row_start, cursor, csr_src, e);

  // GCN layer 1: x[N,64] -> bufB[N,64]
  gemm_kernel<64, 64><<<nblk256, 256, 0, stream>>>(x, W1, bufA, n);
  gcn_agg<64><<<nblk4, 256, 0, stream>>>(bufA, row_start, csr_src, dinv, b1, bufB, n);
  // GCN layer 2
  gemm_kernel<64, 64><<<nblk256, 256, 0, stream>>>(bufB, W2, bufA, n);
  gcn_agg<64><<<nblk4, 256, 0, stream>>>(bufA, row_start, csr_src, dinv, b2, bufB, n);
  // GCN layer 3: -> [N,32]
  gemm_kernel<64, 32><<<nblk256, 256, 0, stream>>>(bufB, W3, bufA, n);
  gcn_agg<32><<<nblk4, 256, 0, stream>>>(bufA, row_start, csr_src, dinv, b3, bufB, n);
  // GAT: g = h3 @ Wg [N,64]
  gemm_kernel<32, 64><<<nblk256, 256, 0, stream>>>(bufB, Wg, bufA, n);
  gat_prep<<<nblk4, 256, 0, stream>>>(bufA, att_src, att_dst, a_s, a_d, n);
  gat_agg<<<nblk4, 256, 0, stream>>>(bufA, a_s, a_d, row_start, csr_src, bg, bufB, n);
  // pool + MLP
  pool_partial<<<PBLK, 256, 0, stream>>>(bufB, partial, n);
  final_kernel<<<1, 64, 0, stream>>>(partial, PBLK, Wc1, bc1, Wc2, bc2, (float*)d_out, n);
}

// Round 2
// 757.408 us; speedup vs baseline: 1.2466x; 1.2466x over previous
//
#include <hip/hip_runtime.h>
#include <hip/hip_bf16.h>
#include <math.h>

// ---------------- graph build ----------------

__global__ __launch_bounds__(256) void count_kernel(const int* __restrict__ dst,
                                                    int* __restrict__ cnt, int e) {
  int i = blockIdx.x * 256 + threadIdx.x;
  if (i < e) atomicAdd(&cnt[dst[i]], 1);
}

// hierarchical scan: pass 1 — per-block (1024-elem chunk) sums
__global__ __launch_bounds__(256) void scan1_kernel(const int* __restrict__ cnt,
                                                    int* __restrict__ blocksum, int n) {
  int idx = blockIdx.x * 1024 + threadIdx.x * 4;
  int4 v = {0, 0, 0, 0};
  if (idx + 3 < n) v = *reinterpret_cast<const int4*>(cnt + idx);
  else {
    if (idx < n) v.x = cnt[idx];
    if (idx + 1 < n) v.y = cnt[idx + 1];
    if (idx + 2 < n) v.z = cnt[idx + 2];
  }
  int s = v.x + v.y + v.z + v.w;
  __shared__ int red[256];
  red[threadIdx.x] = s;
  __syncthreads();
  for (int off = 128; off > 0; off >>= 1) {
    if (threadIdx.x < (unsigned)off) red[threadIdx.x] += red[threadIdx.x + off];
    __syncthreads();
  }
  if (threadIdx.x == 0) blocksum[blockIdx.x] = red[0];
}

// pass 2 — single-block exclusive scan of block sums (nb <= 1024)
__global__ __launch_bounds__(1024) void scan2_kernel(int* __restrict__ blocksum, int nb) {
  __shared__ int s[1024];
  int v = (threadIdx.x < (unsigned)nb) ? blocksum[threadIdx.x] : 0;
  s[threadIdx.x] = v;
  __syncthreads();
  for (int off = 1; off < 1024; off <<= 1) {
    int t = (threadIdx.x >= (unsigned)off) ? s[threadIdx.x - off] : 0;
    __syncthreads();
    s[threadIdx.x] += t;
    __syncthreads();
  }
  if (threadIdx.x < (unsigned)nb) blocksum[threadIdx.x] = s[threadIdx.x] - v;  // exclusive
}

// pass 3 — rescan chunk, add block offset, write exclusive row_start; fused dinv
__global__ __launch_bounds__(256) void scan3_kernel(const int* __restrict__ cnt,
                                                    const int* __restrict__ blocksum,
                                                    int* __restrict__ row_start,
                                                    float* __restrict__ dinv,
                                                    int n, int e) {
  int idx = blockIdx.x * 1024 + threadIdx.x * 4;
  int4 v = {0, 0, 0, 0};
  if (idx + 3 < n) v = *reinterpret_cast<const int4*>(cnt + idx);
  else {
    if (idx < n) v.x = cnt[idx];
    if (idx + 1 < n) v.y = cnt[idx + 1];
    if (idx + 2 < n) v.z = cnt[idx + 2];
  }
  int t0 = v.x, t1 = t0 + v.y, t2 = t1 + v.z, t3 = t2 + v.w;
  __shared__ int s[256];
  s[threadIdx.x] = t3;
  __syncthreads();
  for (int off = 1; off < 256; off <<= 1) {
    int t = (threadIdx.x >= (unsigned)off) ? s[threadIdx.x - off] : 0;
    __syncthreads();
    s[threadIdx.x] += t;
    __syncthreads();
  }
  int excl = s[threadIdx.x] - t3 + blocksum[blockIdx.x];
  if (idx < n)     { row_start[idx]     = excl;      dinv[idx]     = rsqrtf((float)(v.x + 1)); }
  if (idx + 1 < n) { row_start[idx + 1] = excl + t0; dinv[idx + 1] = rsqrtf((float)(v.y + 1)); }
  if (idx + 2 < n) { row_start[idx + 2] = excl + t1; dinv[idx + 2] = rsqrtf((float)(v.z + 1)); }
  if (idx + 3 < n) { row_start[idx + 3] = excl + t2; dinv[idx + 3] = rsqrtf((float)(v.w + 1)); }
  if (blockIdx.x == 0 && threadIdx.x == 0) row_start[n] = e;
}

__global__ __launch_bounds__(256) void fill_kernel(const int* __restrict__ src,
                                                   const int* __restrict__ dst,
                                                   const int* __restrict__ row_start,
                                                   int* __restrict__ cursor,
                                                   int* __restrict__ csr_src, int e) {
  int i = blockIdx.x * 256 + threadIdx.x;
  if (i < e) {
    int d = dst[i];
    int pos = row_start[d] + atomicAdd(&cursor[d], 1);
    csr_src[pos] = src[i];
  }
}

// ---------------- dense GEMM: T = H @ W  (W staged in LDS) ----------------

template <int IN, int OUT>
__global__ __launch_bounds__(256) void gemm_kernel(const float* __restrict__ H,
                                                   const float* __restrict__ W,
                                                   float* __restrict__ T, int n) {
  __shared__ float Ws[IN * OUT];
  for (int i = threadIdx.x; i < IN * OUT; i += 256) Ws[i] = W[i];
  __syncthreads();
  int node = blockIdx.x * 256 + threadIdx.x;
  if (node >= n) return;
  float h[IN];
  const float4* hrow = reinterpret_cast<const float4*>(H + (size_t)node * IN);
#pragma unroll
  for (int k4 = 0; k4 < IN / 4; ++k4) {
    float4 v = hrow[k4];
    h[k4 * 4 + 0] = v.x; h[k4 * 4 + 1] = v.y;
    h[k4 * 4 + 2] = v.z; h[k4 * 4 + 3] = v.w;
  }
  float* out = T + (size_t)node * OUT;
#pragma unroll 1
  for (int j = 0; j < OUT; j += 4) {
    float ax = 0.f, ay = 0.f, az = 0.f, aw = 0.f;
#pragma unroll
    for (int k = 0; k < IN; ++k) {
      float4 w = *reinterpret_cast<const float4*>(&Ws[k * OUT + j]);
      ax = fmaf(h[k], w.x, ax); ay = fmaf(h[k], w.y, ay);
      az = fmaf(h[k], w.z, az); aw = fmaf(h[k], w.w, aw);
    }
    float4 r = {ax, ay, az, aw};
    *reinterpret_cast<float4*>(out + j) = r;
  }
}

// GAT projection GEMM fused with per-node attention coefficients a_s/a_d
__global__ __launch_bounds__(256) void gemm_gat(const float* __restrict__ H,
                                                const float* __restrict__ W,
                                                const float* __restrict__ att_src,
                                                const float* __restrict__ att_dst,
                                                float* __restrict__ g,
                                                float* __restrict__ a_s,
                                                float* __restrict__ a_d, int n) {
  __shared__ float Ws[32 * 64];
  __shared__ float asv[64], adv[64];
  for (int i = threadIdx.x; i < 32 * 64; i += 256) Ws[i] = W[i];
  if (threadIdx.x < 64) {
    asv[threadIdx.x] = att_src[threadIdx.x];
    adv[threadIdx.x] = att_dst[threadIdx.x];
  }
  __syncthreads();
  int node = blockIdx.x * 256 + threadIdx.x;
  if (node >= n) return;
  float h[32];
  const float4* hrow = reinterpret_cast<const float4*>(H + (size_t)node * 32);
#pragma unroll
  for (int k4 = 0; k4 < 8; ++k4) {
    float4 v = hrow[k4];
    h[k4 * 4 + 0] = v.x; h[k4 * 4 + 1] = v.y;
    h[k4 * 4 + 2] = v.z; h[k4 * 4 + 3] = v.w;
  }
  float* out = g + (size_t)node * 64;
  float ps0 = 0.f, ps1 = 0.f, ps2 = 0.f, ps3 = 0.f;
  float pd0 = 0.f, pd1 = 0.f, pd2 = 0.f, pd3 = 0.f;
#pragma unroll 1
  for (int j = 0; j < 64; j += 4) {
    float ax = 0.f, ay = 0.f, az = 0.f, aw = 0.f;
#pragma unroll
    for (int k = 0; k < 32; ++k) {
      float4 w = *reinterpret_cast<const float4*>(&Ws[k * 64 + j]);
      ax = fmaf(h[k], w.x, ax); ay = fmaf(h[k], w.y, ay);
      az = fmaf(h[k], w.z, az); aw = fmaf(h[k], w.w, aw);
    }
    float4 r = {ax, ay, az, aw};
    *reinterpret_cast<float4*>(out + j) = r;
    float cs = ax * asv[j] + ay * asv[j + 1] + az * asv[j + 2] + aw * asv[j + 3];
    float cd = ax * adv[j] + ay * adv[j + 1] + az * adv[j + 2] + aw * adv[j + 3];
    int head = j >> 4;  // wave-uniform
    ps0 += (head == 0) ? cs : 0.f; pd0 += (head == 0) ? cd : 0.f;
    ps1 += (head == 1) ? cs : 0.f; pd1 += (head == 1) ? cd : 0.f;
    ps2 += (head == 2) ? cs : 0.f; pd2 += (head == 2) ? cd : 0.f;
    ps3 += (head == 3) ? cs : 0.f; pd3 += (head == 3) ? cd : 0.f;
  }
  float4 psv = {ps0, ps1, ps2, ps3};
  float4 pdv = {pd0, pd1, pd2, pd3};
  *reinterpret_cast<float4*>(a_s + (size_t)node * 4) = psv;
  *reinterpret_cast<float4*>(a_d + (size_t)node * 4) = pdv;
}

// ---------------- GCN aggregate: out = relu(sum_in + b), wave per node ----------------

template <int C>  // 64 or 32
__global__ __launch_bounds__(256) void gcn_agg(const float* __restrict__ T,
                                               const int* __restrict__ row_start,
                                               const int* __restrict__ csr_src,
                                               const float* __restrict__ dinv,
                                               const float* __restrict__ b,
                                               float* __restrict__ out, int n) {
  constexpr int SUB = 64 / C;  // 1 (C=64) or 2 (C=32)
  int wid = threadIdx.x >> 6;
  int lane = threadIdx.x & 63;
  int node = blockIdx.x * 4 + wid;
  if (node >= n) return;
  int c = lane % C;
  int k = lane / C;
  int rs = row_start[node], re = row_start[node + 1];
  float dn = dinv[node];
  float acc = 0.f;
  if (k == 0) acc = T[(size_t)node * C + c] * dn * dn;  // self-loop
  for (int i = rs + k; i < re; i += SUB) {
    int s = csr_src[i];
    float w = dinv[s] * dn;
    acc = fmaf(T[(size_t)s * C + c], w, acc);
  }
  if (SUB == 2) acc += __shfl_down(acc, 32);
  if (lane < C) out[(size_t)node * C + c] = fmaxf(acc + b[c], 0.f);
}

// ---------------- GAT aggregate ----------------

__device__ __forceinline__ float lrelu(float v) { return v > 0.f ? v : 0.2f * v; }

__global__ __launch_bounds__(256) void gat_agg(const float* __restrict__ g,
                                               const float* __restrict__ a_s,
                                               const float* __restrict__ a_d,
                                               const int* __restrict__ row_start,
                                               const int* __restrict__ csr_src,
                                               const float* __restrict__ bg,
                                               float* __restrict__ out, int n) {
  int wid = threadIdx.x >> 6;
  int lane = threadIdx.x & 63;
  int node = blockIdx.x * 4 + wid;
  if (node >= n) return;
  int h = lane >> 4;
  int rs = row_start[node], re = row_start[node + 1];
  float4 ad4 = *reinterpret_cast<const float4*>(a_d + (size_t)node * 4);
  float4 asn4 = *reinterpret_cast<const float4*>(a_s + (size_t)node * 4);
  // pass A: per-head max over {self, in-edges}
  float4 m4;
  m4.x = lrelu(asn4.x + ad4.x); m4.y = lrelu(asn4.y + ad4.y);
  m4.z = lrelu(asn4.z + ad4.z); m4.w = lrelu(asn4.w + ad4.w);
  for (int i = rs + lane; i < re; i += 64) {
    int s = csr_src[i];
    float4 as4 = *reinterpret_cast<const float4*>(a_s + (size_t)s * 4);
    m4.x = fmaxf(m4.x, lrelu(as4.x + ad4.x));
    m4.y = fmaxf(m4.y, lrelu(as4.y + ad4.y));
    m4.z = fmaxf(m4.z, lrelu(as4.z + ad4.z));
    m4.w = fmaxf(m4.w, lrelu(as4.w + ad4.w));
  }
#pragma unroll
  for (int off = 32; off >= 1; off >>= 1) {
    m4.x = fmaxf(m4.x, __shfl_xor(m4.x, off));
    m4.y = fmaxf(m4.y, __shfl_xor(m4.y, off));
    m4.z = fmaxf(m4.z, __shfl_xor(m4.z, off));
    m4.w = fmaxf(m4.w, __shfl_xor(m4.w, off));
  }
  float m_h  = (h == 0) ? m4.x  : (h == 1) ? m4.y  : (h == 2) ? m4.z  : m4.w;
  float ad_h = (h == 0) ? ad4.x : (h == 1) ? ad4.y : (h == 2) ? ad4.z : ad4.w;
  float as_n = (h == 0) ? asn4.x : (h == 1) ? asn4.y : (h == 2) ? asn4.z : asn4.w;
  // pass B: whole wave per edge; accumulate exp-weights and weighted g rows
  float wself = __expf(lrelu(as_n + ad_h) - m_h);
  float den = wself;
  float acc = wself * g[(size_t)node * 64 + lane];
  for (int i = rs; i < re; ++i) {
    int s = csr_src[i];  // uniform across wave -> broadcast
    float as_h = a_s[(size_t)s * 4 + h];
    float w = __expf(lrelu(as_h + ad_h) - m_h);
    den += w;
    acc = fmaf(w, g[(size_t)s * 64 + lane], acc);
  }
  float o = acc / den + bg[lane];
  out[(size_t)node * 64 + lane] = fmaxf(o, 0.f);
}

// ---------------- pooling + classifier ----------------

__global__ __launch_bounds__(256) void pool_partial(const float* __restrict__ O,
                                                    double* __restrict__ partial, int n) {
  int lane_c = threadIdx.x & 63;
  int sub = threadIdx.x >> 6;  // 0..3
  int chunk = (n + gridDim.x - 1) / gridDim.x;
  int r0 = blockIdx.x * chunk;
  int r1 = min(n, r0 + chunk);
  double acc = 0.0;
  for (int r = r0 + sub; r < r1; r += 4)
    acc += (double)O[(size_t)r * 64 + lane_c];
  __shared__ double red[256];
  red[threadIdx.x] = acc;
  __syncthreads();
  if (sub == 0) {
    acc = red[lane_c] + red[64 + lane_c] + red[128 + lane_c] + red[192 + lane_c];
    partial[(size_t)blockIdx.x * 64 + lane_c] = acc;
  }
}

__global__ __launch_bounds__(64) void final_kernel(const double* __restrict__ partial, int nblocks,
                                                   const float* __restrict__ Wc1,
                                                   const float* __restrict__ bc1,
                                                   const float* __restrict__ Wc2,
                                                   const float* __restrict__ bc2,
                                                   float* __restrict__ out, int n) {
  __shared__ float pooled[64];
  __shared__ float z[32];
  int t = threadIdx.x;
  double s = 0.0;
  for (int b = 0; b < nblocks; ++b) s += partial[(size_t)b * 64 + t];
  pooled[t] = (float)(s / (double)n);
  __syncthreads();
  if (t < 32) {
    double a = 0.0;
    for (int k = 0; k < 64; ++k) a += (double)pooled[k] * (double)Wc1[k * 32 + t];
    z[t] = fmaxf((float)a + bc1[t], 0.f);
  }
  __syncthreads();
  if (t < 2) {
    double a = 0.0;
    for (int j = 0; j < 32; ++j) a += (double)z[j] * (double)Wc2[j * 2 + t];
    out[t] = (float)a + bc2[t];
  }
}

// ---------------- launch ----------------

extern "C" void kernel_launch(void* const* d_in, const int* in_sizes, int n_in,
                              void* d_out, int out_size, void* d_ws, size_t ws_size,
                              hipStream_t stream) {
  const float* x   = (const float*)d_in[0];
  const int* eidx  = (const int*)d_in[1];
  const float* W1  = (const float*)d_in[2];
  const float* b1  = (const float*)d_in[3];
  const float* W2  = (const float*)d_in[4];
  const float* b2  = (const float*)d_in[5];
  const float* W3  = (const float*)d_in[6];
  const float* b3  = (const float*)d_in[7];
  const float* Wg  = (const float*)d_in[8];
  const float* att_src = (const float*)d_in[9];
  const float* att_dst = (const float*)d_in[10];
  const float* bg  = (const float*)d_in[11];
  const float* Wc1 = (const float*)d_in[12];
  const float* bc1 = (const float*)d_in[13];
  const float* Wc2 = (const float*)d_in[14];
  const float* bc2 = (const float*)d_in[15];

  const int n = in_sizes[0] / 64;   // 100000
  const int e = in_sizes[1] / 2;    // 1200000
  const int* src = eidx;
  const int* dst = eidx + e;

  char* ws = (char*)d_ws;
  size_t off = 0;
  auto alloc = [&](size_t bytes) {
    void* p = ws + off;
    off += (bytes + 255) & ~(size_t)255;
    return p;
  };
  const int nb1024 = (n + 1023) / 1024;
  int*    cnt       = (int*)alloc((size_t)n * 4);
  int*    row_start = (int*)alloc(((size_t)n + 1) * 4);
  int*    cursor    = (int*)alloc((size_t)n * 4);
  int*    csr_src   = (int*)alloc((size_t)e * 4);
  float*  dinv      = (float*)alloc((size_t)n * 4);
  int*    blocksum  = (int*)alloc((size_t)nb1024 * 4);
  float*  bufA      = (float*)alloc((size_t)n * 64 * 4);
  float*  bufB      = (float*)alloc((size_t)n * 64 * 4);
  float*  a_s       = (float*)alloc((size_t)n * 4 * 4);
  float*  a_d       = (float*)alloc((size_t)n * 4 * 4);
  const int PBLK = 128;
  double* partial   = (double*)alloc((size_t)PBLK * 64 * 8);

  hipMemsetAsync(cnt, 0, (size_t)n * 4, stream);
  hipMemsetAsync(cursor, 0, (size_t)n * 4, stream);

  int eblk = (e + 255) / 256;
  int nblk256 = (n + 255) / 256;
  int nblk4 = (n + 3) / 4;

  count_kernel<<<eblk, 256, 0, stream>>>(dst, cnt, e);
  scan1_kernel<<<nb1024, 256, 0, stream>>>(cnt, blocksum, n);
  scan2_kernel<<<1, 1024, 0, stream>>>(blocksum, nb1024);
  scan3_kernel<<<nb1024, 256, 0, stream>>>(cnt, blocksum, row_start, dinv, n, e);
  fill_kernel<<<eblk, 256, 0, stream>>>(src, dst, row_start, cursor, csr_src, e);

  // GCN layer 1: x[N,64] -> bufB[N,64]
  gemm_kernel<64, 64><<<nblk256, 256, 0, stream>>>(x, W1, bufA, n);
  gcn_agg<64><<<nblk4, 256, 0, stream>>>(bufA, row_start, csr_src, dinv, b1, bufB, n);
  // GCN layer 2
  gemm_kernel<64, 64><<<nblk256, 256, 0, stream>>>(bufB, W2, bufA, n);
  gcn_agg<64><<<nblk4, 256, 0, stream>>>(bufA, row_start, csr_src, dinv, b2, bufB, n);
  // GCN layer 3: -> [N,32]
  gemm_kernel<64, 32><<<nblk256, 256, 0, stream>>>(bufB, W3, bufA, n);
  gcn_agg<32><<<nblk4, 256, 0, stream>>>(bufA, row_start, csr_src, dinv, b3, bufB, n);
  // GAT: g = h3 @ Wg [N,64] + fused a_s/a_d
  gemm_gat<<<nblk256, 256, 0, stream>>>(bufB, Wg, att_src, att_dst, bufA, a_s, a_d, n);
  gat_agg<<<nblk4, 256, 0, stream>>>(bufA, a_s, a_d, row_start, csr_src, bg, bufB, n);
  // pool + MLP
  pool_partial<<<PBLK, 256, 0, stream>>>(bufB, partial, n);
  final_kernel<<<1, 64, 0, stream>>>(partial, PBLK, Wc1, bc1, Wc2, bc2, (float*)d_out, n);
}